// Round 2
// baseline (474.163 us; speedup 1.0000x reference)
//
#include <hip/hip_runtime.h>
#include <hip/hip_bf16.h>

// GCN 3-layer forward. Round 8b (compile fix of round 8):
//  - bf16 layer-boundary buffers: gather writes bf16 H (same rounding point the GEMM
//    A-staging already applied), GEMM reads bf16 A directly -> ~77 MB less traffic
//  - gather: software-pipelined ecsr chunk loads (prefetch next chunk under gathers)
//  - nontemporal loads/stores on streaming data (ecsr, A-staging, outputs) to keep
//    per-XCD L2 for the randomly gathered S table
//  - nontemporal builtins require native ext_vector types, not HIP_vector_type

#define EPB 8192   // edges per binning block

typedef unsigned int u32x4 __attribute__((ext_vector_type(4)));
typedef unsigned int u32x2 __attribute__((ext_vector_type(2)));
typedef float        f32x4 __attribute__((ext_vector_type(4)));

__device__ __forceinline__ unsigned short f2bf(float f) {
    unsigned int u = __float_as_uint(f);
    unsigned int r = (u + 0x7fffu + ((u >> 16) & 1u)) >> 16;   // RNE
    return (unsigned short)r;
}

using frag_ab = __attribute__((ext_vector_type(8))) short;   // 8 bf16
using frag_cd = __attribute__((ext_vector_type(4))) float;   // 4 fp32

// ---------------- MFMA GEMM: C[M,BN](bf16) = A[M,K] @ WT[BN,K](bf16)^T ----------------
// BM=128, BK=64; 4 waves, wave w owns rows [w*32, w*32+32) as two 16-row tiles.
// A is fp32 (layer 1) or bf16 (layers 2/3) selected by ABF16.
template <int BN, bool ABF16>
__global__ __launch_bounds__(256) void mfma_gemm_kernel(
    const void* __restrict__ Av, const unsigned short* __restrict__ WT,
    unsigned short* __restrict__ C, int M, int K)
{
    constexpr int BM = 128, BK = 64;
    constexpr int LDA = BK + 8;                    // 72: +16B pad, 2-way LDS conflict (free)
    __shared__ unsigned short As[BM * LDA];
    __shared__ unsigned short Bs[BN * LDA];

    const int tid = threadIdx.x;
    const int wave = tid >> 6;
    const int lane = tid & 63;
    const int quad = lane >> 4;
    const int l16 = lane & 15;
    const int m0 = blockIdx.x * BM;

    frag_cd acc[2][BN / 16];
#pragma unroll
    for (int rt = 0; rt < 2; ++rt)
#pragma unroll
        for (int f = 0; f < BN / 16; ++f) acc[rt][f] = (frag_cd){0.f, 0.f, 0.f, 0.f};

    for (int k0 = 0; k0 < K; k0 += BK) {
        if constexpr (!ABF16) {
            // stage A tile (128x64 fp32 -> bf16): 8 float4 per thread
            const float* A = (const float*)Av;
#pragma unroll
            for (int i = 0; i < 8; ++i) {
                const int linear = (i * 256 + tid) * 4;
                const int r = linear >> 6;
                const int c = linear & 63;
                const int row = m0 + r;
                f32x4 v = (f32x4){0.f, 0.f, 0.f, 0.f};
                if (row < M) v = __builtin_nontemporal_load((const f32x4*)&A[(size_t)row * K + k0 + c]);
                ushort4 u;
                u.x = f2bf(v.x); u.y = f2bf(v.y); u.z = f2bf(v.z); u.w = f2bf(v.w);
                *(ushort4*)&As[r * LDA + c] = u;
            }
        } else {
            // stage A tile (128x64 bf16): 4 uint4 per thread, pure copy
            const unsigned short* A = (const unsigned short*)Av;
#pragma unroll
            for (int i = 0; i < 4; ++i) {
                const int linear = (i * 256 + tid) * 8;
                const int r = linear >> 6;
                const int c = linear & 63;
                const int row = m0 + r;
                u32x4 u = (u32x4){0u, 0u, 0u, 0u};
                if (row < M) u = __builtin_nontemporal_load((const u32x4*)&A[(size_t)row * K + k0 + c]);
                *(u32x4*)&As[r * LDA + c] = u;
            }
        }
        // stage B tile (BN x 64 bf16): BN/32 uint4 per thread
#pragma unroll
        for (int i = 0; i < BN / 32; ++i) {
            const int linear = (i * 256 + tid) * 8;
            const int n = linear >> 6;
            const int c = linear & 63;
            const u32x4 u = *(const u32x4*)&WT[(size_t)n * K + k0 + c];
            *(u32x4*)&Bs[n * LDA + c] = u;
        }
        __syncthreads();

#pragma unroll
        for (int ks = 0; ks < 2; ++ks) {
            const int kk = ks * 32 + quad * 8;
            const frag_ab a0 = *(const frag_ab*)&As[(wave * 32 + l16) * LDA + kk];
            const frag_ab a1 = *(const frag_ab*)&As[(wave * 32 + 16 + l16) * LDA + kk];
#pragma unroll
            for (int f = 0; f < BN / 16; ++f) {
                const frag_ab b = *(const frag_ab*)&Bs[(f * 16 + l16) * LDA + kk];
                acc[0][f] = __builtin_amdgcn_mfma_f32_16x16x32_bf16(a0, b, acc[0][f], 0, 0, 0);
                acc[1][f] = __builtin_amdgcn_mfma_f32_16x16x32_bf16(a1, b, acc[1][f], 0, 0, 0);
            }
        }
        __syncthreads();
    }

#pragma unroll
    for (int rt = 0; rt < 2; ++rt)
#pragma unroll
        for (int f = 0; f < BN / 16; ++f)
#pragma unroll
            for (int r = 0; r < 4; ++r) {
                const int row = m0 + wave * 32 + rt * 16 + quad * 4 + r;
                if (row < M) C[(size_t)row * BN + f * 16 + l16] = f2bf(acc[rt][f][r]);
            }
}

// ---------------- weight transpose+convert ----------------
__global__ __launch_bounds__(256) void wt_kernel(
    const float* __restrict__ W1, const float* __restrict__ W2, const float* __restrict__ W3,
    unsigned short* __restrict__ WT1, unsigned short* __restrict__ WT2, unsigned short* __restrict__ WT3)
{
    const int i = blockIdx.x * 256 + threadIdx.x;
    const float* W; unsigned short* WT; int K, N, j;
    if (i < 32768)      { W = W1; WT = WT1; K = 256; N = 128; j = i; }
    else if (i < 40960) { W = W2; WT = WT2; K = 128; N = 64;  j = i - 32768; }
    else if (i < 45056) { W = W3; WT = WT3; K = 64;  N = 64;  j = i - 40960; }
    else return;
    const int n = j / K, k = j % K;
    WT[j] = f2bf(W[k * N + n]);
}

// ---------------- phase 1: per-block bucket histogram (LDS atomics only) ----------------
__global__ __launch_bounds__(256) void count_kernel(
    const int* __restrict__ dst, int* __restrict__ cmat, int E, int nblk, int nbuck)
{
    __shared__ int hist[1600];
    for (int i = threadIdx.x; i < nbuck; i += 256) hist[i] = 0;
    __syncthreads();
    const int base = blockIdx.x * EPB;
    const int end = min(base + EPB, E);
    for (int e = base + threadIdx.x; e < end; e += 256)
        atomicAdd(&hist[dst[e] >> 6], 1);
    __syncthreads();
    for (int i = threadIdx.x; i < nbuck; i += 256)
        cmat[(size_t)i * nblk + blockIdx.x] = hist[i];
}

// ---------------- scan over cmat (L = nbuck*nblk) ----------------
__global__ __launch_bounds__(256) void scanA_kernel(
    int* __restrict__ data, int* __restrict__ psum, int L)
{
    __shared__ int tmp[256];
    const int b0 = blockIdx.x * 1024 + threadIdx.x * 4;
    int v[4] = {0, 0, 0, 0};
    if (b0 + 3 < L) { const int4 t = *(const int4*)&data[b0]; v[0]=t.x; v[1]=t.y; v[2]=t.z; v[3]=t.w; }
    else { for (int i = 0; i < 4; ++i) if (b0 + i < L) v[i] = data[b0 + i]; }
    const int s = v[0] + v[1] + v[2] + v[3];
    tmp[threadIdx.x] = s;
    __syncthreads();
#pragma unroll
    for (int d = 1; d < 256; d <<= 1) {
        const int t = (threadIdx.x >= d) ? tmp[threadIdx.x - d] : 0;
        __syncthreads();
        tmp[threadIdx.x] += t;
        __syncthreads();
    }
    int run = tmp[threadIdx.x] - s;
    int o[4];
#pragma unroll
    for (int i = 0; i < 4; ++i) { o[i] = run; run += v[i]; }
    if (b0 + 3 < L) { *(int4*)&data[b0] = make_int4(o[0], o[1], o[2], o[3]); }
    else { for (int i = 0; i < 4; ++i) if (b0 + i < L) data[b0 + i] = o[i]; }
    if (threadIdx.x == 255) psum[blockIdx.x] = tmp[255];
}

__global__ __launch_bounds__(1024) void scanB_kernel(int* __restrict__ psum, int nb)
{
    __shared__ int tmp[1024];
    const int v = ((int)threadIdx.x < nb) ? psum[threadIdx.x] : 0;
    tmp[threadIdx.x] = v;
    __syncthreads();
#pragma unroll
    for (int d = 1; d < 1024; d <<= 1) {
        const int t = ((int)threadIdx.x >= d) ? tmp[threadIdx.x - d] : 0;
        __syncthreads();
        tmp[threadIdx.x] += t;
        __syncthreads();
    }
    if ((int)threadIdx.x < nb) psum[threadIdx.x] = tmp[threadIdx.x] - v;
}

__global__ __launch_bounds__(256) void scanC_kernel(
    int* __restrict__ data, const int* __restrict__ psum, int L)
{
    const int i = blockIdx.x * 256 + threadIdx.x;
    if (i < L) data[i] += psum[i >> 10];
}

// ---------------- phase 2: bucket placement (LDS cursors, near-coalesced writes) ----------------
// ebuck[pos] = { (src<<6) | (dst&63), bits(w) }, sorted by bucket = dst>>6
__global__ __launch_bounds__(256) void place_kernel(
    const int* __restrict__ src, const int* __restrict__ dst, const float* __restrict__ ew,
    const int* __restrict__ cmat, uint2* __restrict__ ebuck, int E, int nblk, int nbuck)
{
    __shared__ int cursor[1600];
    const int k = blockIdx.x;
    for (int i = threadIdx.x; i < nbuck; i += 256)
        cursor[i] = cmat[(size_t)i * nblk + k];
    __syncthreads();
    const int base = k * EPB;
    const int end = min(base + EPB, E);
    for (int e = base + threadIdx.x; e < end; e += 256) {
        const int d = dst[e];
        const int b = d >> 6;
        const int pos = atomicAdd(&cursor[b], 1);
        ebuck[pos] = make_uint2(((unsigned)src[e] << 6) | (unsigned)(d & 63),
                                __float_as_uint(ew[e]));
    }
}

// ---------------- phase 3: per-node offs (LDS hist + wave scan) + within-bucket sort ----------------
__global__ __launch_bounds__(256) void sort2_kernel(
    const uint2* __restrict__ ebuck, const int* __restrict__ cmat,
    int* __restrict__ offs, uint2* __restrict__ ecsr,
    int N, int nblk, int nbuck, int E)
{
    __shared__ int cnt[64];
    __shared__ int cur[64];
    const int b = blockIdx.x;
    const int node0 = b << 6;
    const int nn = min(64, N - node0);
    const int j0 = cmat[(size_t)b * nblk];
    const int j1 = (b + 1 < nbuck) ? cmat[(size_t)(b + 1) * nblk] : E;

    if (threadIdx.x < 64) cnt[threadIdx.x] = 0;
    __syncthreads();
    for (int j = j0 + (int)threadIdx.x; j < j1; j += 256)
        atomicAdd(&cnt[ebuck[j].x & 63u], 1);
    __syncthreads();

    if (threadIdx.x < 64) {            // single wave: wave-synchronous scan
        const int myv = cnt[threadIdx.x];
        int v = myv;
#pragma unroll
        for (int d = 1; d < 64; d <<= 1) {
            const int t = __shfl_up(v, d, 64);
            if ((int)threadIdx.x >= d) v += t;
        }
        const int base = j0 + v - myv;   // exclusive
        cur[threadIdx.x] = base;
        if ((int)threadIdx.x < nn) offs[node0 + threadIdx.x] = base;
        if (threadIdx.x == 0 && b == nbuck - 1) offs[N] = E;
    }
    __syncthreads();

    for (int j = j0 + (int)threadIdx.x; j < j1; j += 256) {
        const uint2 ed = ebuck[j];
        const int pos = atomicAdd(&cur[ed.x & 63u], 1);
        ecsr[pos] = make_uint2(ed.x >> 6, ed.y);
    }
}

// ---------------- fused gather-aggregate (bf16 S) + bias + relu ----------------
// OUT_T = unsigned short (bf16, layers 1-2) or float (fp32, final layer).
// Next chunk's ecsr load is software-pipelined under the current chunk's gathers.
template <int D, int LOGT, bool RELU, typename OUT_T>
__global__ __launch_bounds__(256) void gather_agg_kernel(
    const unsigned short* __restrict__ S, const int* __restrict__ offs,
    const uint2* __restrict__ ecsr,
    const float* __restrict__ bias, OUT_T* __restrict__ out, int N)
{
    constexpr int TPN = 1 << LOGT;
    const int gid = blockIdx.x * 256 + threadIdx.x;
    const int node = gid >> LOGT;
    if (node >= N) return;
    const int lane = gid & (TPN - 1);
    const int c8 = lane << 3;

    const int j0 = offs[node];
    const int j1 = offs[node + 1];

    float acc[8];
#pragma unroll
    for (int c = 0; c < 8; ++c) acc[c] = 0.f;

    int jb = j0;
    u32x2 p = (u32x2){0u, 0u};
    if (jb + lane < j1) p = __builtin_nontemporal_load((const u32x2*)&ecsr[jb + lane]);

    const int nfull = (j1 - j0) >> LOGT;
    for (int ch = 0; ch < nfull; ++ch) {
        const int jn = jb + TPN;
        u32x2 pn = (u32x2){0u, 0u};
        if (jn + lane < j1) pn = __builtin_nontemporal_load((const u32x2*)&ecsr[jn + lane]);  // prefetch
        const int myc = (int)p.x;
        const float myw = __uint_as_float(p.y);
#pragma unroll
        for (int t = 0; t < TPN; ++t) {
            const int s = __shfl(myc, t, TPN);
            const float w = __shfl(myw, t, TPN);
            const uint4 v = *(const uint4*)&S[(size_t)s * D + c8];
#pragma unroll
            for (int q = 0; q < 4; ++q) {
                const unsigned int u = (&v.x)[q];
                acc[q * 2 + 0] += w * __uint_as_float(u << 16);
                acc[q * 2 + 1] += w * __uint_as_float(u & 0xffff0000u);
            }
        }
        p = pn; jb = jn;
    }
    {   // tail: p already holds the (guarded) loads for [jb, j1)
        const int cnt = j1 - jb;
        const int myc = (int)p.x;
        const float myw = __uint_as_float(p.y);
        for (int t = 0; t < cnt; ++t) {
            const int s = __shfl(myc, t, TPN);
            const float w = __shfl(myw, t, TPN);
            const uint4 v = *(const uint4*)&S[(size_t)s * D + c8];
#pragma unroll
            for (int q = 0; q < 4; ++q) {
                const unsigned int u = (&v.x)[q];
                acc[q * 2 + 0] += w * __uint_as_float(u << 16);
                acc[q * 2 + 1] += w * __uint_as_float(u & 0xffff0000u);
            }
        }
    }

#pragma unroll
    for (int c = 0; c < 8; ++c) {
        float v = acc[c] + bias[c8 + c];
        if (RELU) v = fmaxf(v, 0.f);
        acc[c] = v;
    }
    if constexpr (sizeof(OUT_T) == 2) {
        u32x4 u;
        u.x = ((unsigned)f2bf(acc[1]) << 16) | (unsigned)f2bf(acc[0]);
        u.y = ((unsigned)f2bf(acc[3]) << 16) | (unsigned)f2bf(acc[2]);
        u.z = ((unsigned)f2bf(acc[5]) << 16) | (unsigned)f2bf(acc[4]);
        u.w = ((unsigned)f2bf(acc[7]) << 16) | (unsigned)f2bf(acc[6]);
        __builtin_nontemporal_store(u, (u32x4*)&((unsigned short*)out)[(size_t)node * D + c8]);
    } else {
        float* op = (float*)out + (size_t)node * D + c8;
        __builtin_nontemporal_store((f32x4){acc[0], acc[1], acc[2], acc[3]}, (f32x4*)op);
        __builtin_nontemporal_store((f32x4){acc[4], acc[5], acc[6], acc[7]}, (f32x4*)op + 1);
    }
}

extern "C" void kernel_launch(void* const* d_in, const int* in_sizes, int n_in,
                              void* d_out, int out_size, void* d_ws, size_t ws_size,
                              hipStream_t stream)
{
    const float* x    = (const float*)d_in[0];
    const int*   esrc = (const int*)  d_in[1];
    const int*   edst = (const int*)  d_in[2];
    const float* ew   = (const float*)d_in[3];
    const float* W1   = (const float*)d_in[4];
    const float* b1   = (const float*)d_in[5];
    const float* W2   = (const float*)d_in[6];
    const float* b2   = (const float*)d_in[7];
    const float* W3   = (const float*)d_in[8];
    const float* b3   = (const float*)d_in[9];

    const int N = in_sizes[0] / 256;   // 100000
    const int E = in_sizes[1];         // 1600000

    const int nbuck = (N + 63) >> 6;               // 1563
    const int nblk = (E + EPB - 1) / EPB;          // 196
    const int L = nbuck * nblk;

    // workspace layout (all bf16 intermediates now)
    unsigned short* Sb = (unsigned short*)d_ws;            // N*128 bf16 support
    unsigned short* Hb = Sb + (size_t)N * 128;             // N*128 bf16 hidden
    unsigned short* WT1 = Hb + (size_t)N * 128;
    unsigned short* WT2 = WT1 + 256 * 128;
    unsigned short* WT3 = WT2 + 128 * 64;
    uint2* ebuck = (uint2*)(WT3 + 64 * 64);                // E bucket-sorted
    uint2* ecsr  = ebuck + E;                              // E node-sorted (src, w)
    int* offs   = (int*)(ecsr + E);                        // N+1 (pad 4)
    int* cmat   = offs + N + 4;                            // nbuck*nblk
    int* psum   = cmat + ((L + 3) & ~3);                   // up to 1024
    float* out  = (float*)d_out;

    const dim3 blk(256);
    const int mblocks = (N + 127) / 128;                   // 782

    // ---- prep: weights + bucket sort + per-node offs ----
    wt_kernel<<<(45056 + 255) / 256, blk, 0, stream>>>(W1, W2, W3, WT1, WT2, WT3);
    count_kernel<<<nblk, blk, 0, stream>>>(edst, cmat, E, nblk, nbuck);
    scanA_kernel<<<(L + 1023) / 1024, blk, 0, stream>>>(cmat, psum, L);
    scanB_kernel<<<1, 1024, 0, stream>>>(psum, (L + 1023) / 1024);
    scanC_kernel<<<(L + 255) / 256, blk, 0, stream>>>(cmat, psum, L);
    place_kernel<<<nblk, blk, 0, stream>>>(esrc, edst, ew, cmat, ebuck, E, nblk, nbuck);
    sort2_kernel<<<nbuck, blk, 0, stream>>>(ebuck, cmat, offs, ecsr, N, nblk, nbuck, E);

    // ---- layer 1: 256 -> 128 ----
    mfma_gemm_kernel<128, false><<<mblocks, blk, 0, stream>>>(x, WT1, Sb, N, 256);
    gather_agg_kernel<128, 4, true, unsigned short><<<((N * 16) + 255) / 256, blk, 0, stream>>>(
        Sb, offs, ecsr, b1, Hb, N);

    // ---- layer 2: 128 -> 64 ----
    mfma_gemm_kernel<64, true><<<mblocks, blk, 0, stream>>>(Hb, WT2, Sb, N, 128);
    gather_agg_kernel<64, 3, true, unsigned short><<<((N * 8) + 255) / 256, blk, 0, stream>>>(
        Sb, offs, ecsr, b2, Hb, N);

    // ---- layer 3: 64 -> 64 ----
    mfma_gemm_kernel<64, true><<<mblocks, blk, 0, stream>>>(Hb, WT3, Sb, N, 64);
    gather_agg_kernel<64, 3, false, float><<<((N * 8) + 255) / 256, blk, 0, stream>>>(
        Sb, offs, ecsr, b3, out, N);
}

// Round 3
// 461.265 us; speedup vs baseline: 1.0280x; 1.0280x over previous
//
#include <hip/hip_runtime.h>
#include <hip/hip_bf16.h>

// GCN 3-layer forward. Round 9:
//  - keep round-8's bf16 layer-boundary buffers (gather writes bf16 H, GEMM reads bf16 A)
//  - revert gather loop to round-7 structure (no prefetch pipeline, plain loads):
//    round-8's guarded prefetch cost VGPR 48->68, occupancy 46->27%, dur 73->83us
//  - no nontemporal hints (confounded with the regression)

#define EPB 8192   // edges per binning block

__device__ __forceinline__ unsigned short f2bf(float f) {
    unsigned int u = __float_as_uint(f);
    unsigned int r = (u + 0x7fffu + ((u >> 16) & 1u)) >> 16;   // RNE
    return (unsigned short)r;
}

using frag_ab = __attribute__((ext_vector_type(8))) short;   // 8 bf16
using frag_cd = __attribute__((ext_vector_type(4))) float;   // 4 fp32

// ---------------- MFMA GEMM: C[M,BN](bf16) = A[M,K] @ WT[BN,K](bf16)^T ----------------
// BM=128, BK=64; 4 waves, wave w owns rows [w*32, w*32+32) as two 16-row tiles.
// A is fp32 (layer 1) or bf16 (layers 2/3) selected by ABF16.
template <int BN, bool ABF16>
__global__ __launch_bounds__(256) void mfma_gemm_kernel(
    const void* __restrict__ Av, const unsigned short* __restrict__ WT,
    unsigned short* __restrict__ C, int M, int K)
{
    constexpr int BM = 128, BK = 64;
    constexpr int LDA = BK + 8;                    // 72: +16B pad, 2-way LDS conflict (free)
    __shared__ unsigned short As[BM * LDA];
    __shared__ unsigned short Bs[BN * LDA];

    const int tid = threadIdx.x;
    const int wave = tid >> 6;
    const int lane = tid & 63;
    const int quad = lane >> 4;
    const int l16 = lane & 15;
    const int m0 = blockIdx.x * BM;

    frag_cd acc[2][BN / 16];
#pragma unroll
    for (int rt = 0; rt < 2; ++rt)
#pragma unroll
        for (int f = 0; f < BN / 16; ++f) acc[rt][f] = (frag_cd){0.f, 0.f, 0.f, 0.f};

    for (int k0 = 0; k0 < K; k0 += BK) {
        if constexpr (!ABF16) {
            // stage A tile (128x64 fp32 -> bf16): 8 float4 per thread
            const float* A = (const float*)Av;
#pragma unroll
            for (int i = 0; i < 8; ++i) {
                const int linear = (i * 256 + tid) * 4;
                const int r = linear >> 6;
                const int c = linear & 63;
                const int row = m0 + r;
                float4 v = make_float4(0.f, 0.f, 0.f, 0.f);
                if (row < M) v = *(const float4*)&A[(size_t)row * K + k0 + c];
                ushort4 u;
                u.x = f2bf(v.x); u.y = f2bf(v.y); u.z = f2bf(v.z); u.w = f2bf(v.w);
                *(ushort4*)&As[r * LDA + c] = u;
            }
        } else {
            // stage A tile (128x64 bf16): 4 uint4 per thread, pure copy
            const unsigned short* A = (const unsigned short*)Av;
#pragma unroll
            for (int i = 0; i < 4; ++i) {
                const int linear = (i * 256 + tid) * 8;
                const int r = linear >> 6;
                const int c = linear & 63;
                const int row = m0 + r;
                uint4 u = make_uint4(0u, 0u, 0u, 0u);
                if (row < M) u = *(const uint4*)&A[(size_t)row * K + k0 + c];
                *(uint4*)&As[r * LDA + c] = u;
            }
        }
        // stage B tile (BN x 64 bf16): BN/32 uint4 per thread
#pragma unroll
        for (int i = 0; i < BN / 32; ++i) {
            const int linear = (i * 256 + tid) * 8;
            const int n = linear >> 6;
            const int c = linear & 63;
            const uint4 u = *(const uint4*)&WT[(size_t)n * K + k0 + c];
            *(uint4*)&Bs[n * LDA + c] = u;
        }
        __syncthreads();

#pragma unroll
        for (int ks = 0; ks < 2; ++ks) {
            const int kk = ks * 32 + quad * 8;
            const frag_ab a0 = *(const frag_ab*)&As[(wave * 32 + l16) * LDA + kk];
            const frag_ab a1 = *(const frag_ab*)&As[(wave * 32 + 16 + l16) * LDA + kk];
#pragma unroll
            for (int f = 0; f < BN / 16; ++f) {
                const frag_ab b = *(const frag_ab*)&Bs[(f * 16 + l16) * LDA + kk];
                acc[0][f] = __builtin_amdgcn_mfma_f32_16x16x32_bf16(a0, b, acc[0][f], 0, 0, 0);
                acc[1][f] = __builtin_amdgcn_mfma_f32_16x16x32_bf16(a1, b, acc[1][f], 0, 0, 0);
            }
        }
        __syncthreads();
    }

#pragma unroll
    for (int rt = 0; rt < 2; ++rt)
#pragma unroll
        for (int f = 0; f < BN / 16; ++f)
#pragma unroll
            for (int r = 0; r < 4; ++r) {
                const int row = m0 + wave * 32 + rt * 16 + quad * 4 + r;
                if (row < M) C[(size_t)row * BN + f * 16 + l16] = f2bf(acc[rt][f][r]);
            }
}

// ---------------- weight transpose+convert ----------------
__global__ __launch_bounds__(256) void wt_kernel(
    const float* __restrict__ W1, const float* __restrict__ W2, const float* __restrict__ W3,
    unsigned short* __restrict__ WT1, unsigned short* __restrict__ WT2, unsigned short* __restrict__ WT3)
{
    const int i = blockIdx.x * 256 + threadIdx.x;
    const float* W; unsigned short* WT; int K, N, j;
    if (i < 32768)      { W = W1; WT = WT1; K = 256; N = 128; j = i; }
    else if (i < 40960) { W = W2; WT = WT2; K = 128; N = 64;  j = i - 32768; }
    else if (i < 45056) { W = W3; WT = WT3; K = 64;  N = 64;  j = i - 40960; }
    else return;
    const int n = j / K, k = j % K;
    WT[j] = f2bf(W[k * N + n]);
}

// ---------------- phase 1: per-block bucket histogram (LDS atomics only) ----------------
__global__ __launch_bounds__(256) void count_kernel(
    const int* __restrict__ dst, int* __restrict__ cmat, int E, int nblk, int nbuck)
{
    __shared__ int hist[1600];
    for (int i = threadIdx.x; i < nbuck; i += 256) hist[i] = 0;
    __syncthreads();
    const int base = blockIdx.x * EPB;
    const int end = min(base + EPB, E);
    for (int e = base + threadIdx.x; e < end; e += 256)
        atomicAdd(&hist[dst[e] >> 6], 1);
    __syncthreads();
    for (int i = threadIdx.x; i < nbuck; i += 256)
        cmat[(size_t)i * nblk + blockIdx.x] = hist[i];
}

// ---------------- scan over cmat (L = nbuck*nblk) ----------------
__global__ __launch_bounds__(256) void scanA_kernel(
    int* __restrict__ data, int* __restrict__ psum, int L)
{
    __shared__ int tmp[256];
    const int b0 = blockIdx.x * 1024 + threadIdx.x * 4;
    int v[4] = {0, 0, 0, 0};
    if (b0 + 3 < L) { const int4 t = *(const int4*)&data[b0]; v[0]=t.x; v[1]=t.y; v[2]=t.z; v[3]=t.w; }
    else { for (int i = 0; i < 4; ++i) if (b0 + i < L) v[i] = data[b0 + i]; }
    const int s = v[0] + v[1] + v[2] + v[3];
    tmp[threadIdx.x] = s;
    __syncthreads();
#pragma unroll
    for (int d = 1; d < 256; d <<= 1) {
        const int t = (threadIdx.x >= d) ? tmp[threadIdx.x - d] : 0;
        __syncthreads();
        tmp[threadIdx.x] += t;
        __syncthreads();
    }
    int run = tmp[threadIdx.x] - s;
    int o[4];
#pragma unroll
    for (int i = 0; i < 4; ++i) { o[i] = run; run += v[i]; }
    if (b0 + 3 < L) { *(int4*)&data[b0] = make_int4(o[0], o[1], o[2], o[3]); }
    else { for (int i = 0; i < 4; ++i) if (b0 + i < L) data[b0 + i] = o[i]; }
    if (threadIdx.x == 255) psum[blockIdx.x] = tmp[255];
}

__global__ __launch_bounds__(1024) void scanB_kernel(int* __restrict__ psum, int nb)
{
    __shared__ int tmp[1024];
    const int v = ((int)threadIdx.x < nb) ? psum[threadIdx.x] : 0;
    tmp[threadIdx.x] = v;
    __syncthreads();
#pragma unroll
    for (int d = 1; d < 1024; d <<= 1) {
        const int t = ((int)threadIdx.x >= d) ? tmp[threadIdx.x - d] : 0;
        __syncthreads();
        tmp[threadIdx.x] += t;
        __syncthreads();
    }
    if ((int)threadIdx.x < nb) psum[threadIdx.x] = tmp[threadIdx.x] - v;
}

__global__ __launch_bounds__(256) void scanC_kernel(
    int* __restrict__ data, const int* __restrict__ psum, int L)
{
    const int i = blockIdx.x * 256 + threadIdx.x;
    if (i < L) data[i] += psum[i >> 10];
}

// ---------------- phase 2: bucket placement (LDS cursors, near-coalesced writes) ----------------
// ebuck[pos] = { (src<<6) | (dst&63), bits(w) }, sorted by bucket = dst>>6
__global__ __launch_bounds__(256) void place_kernel(
    const int* __restrict__ src, const int* __restrict__ dst, const float* __restrict__ ew,
    const int* __restrict__ cmat, uint2* __restrict__ ebuck, int E, int nblk, int nbuck)
{
    __shared__ int cursor[1600];
    const int k = blockIdx.x;
    for (int i = threadIdx.x; i < nbuck; i += 256)
        cursor[i] = cmat[(size_t)i * nblk + k];
    __syncthreads();
    const int base = k * EPB;
    const int end = min(base + EPB, E);
    for (int e = base + threadIdx.x; e < end; e += 256) {
        const int d = dst[e];
        const int b = d >> 6;
        const int pos = atomicAdd(&cursor[b], 1);
        ebuck[pos] = make_uint2(((unsigned)src[e] << 6) | (unsigned)(d & 63),
                                __float_as_uint(ew[e]));
    }
}

// ---------------- phase 3: per-node offs (LDS hist + wave scan) + within-bucket sort ----------------
__global__ __launch_bounds__(256) void sort2_kernel(
    const uint2* __restrict__ ebuck, const int* __restrict__ cmat,
    int* __restrict__ offs, uint2* __restrict__ ecsr,
    int N, int nblk, int nbuck, int E)
{
    __shared__ int cnt[64];
    __shared__ int cur[64];
    const int b = blockIdx.x;
    const int node0 = b << 6;
    const int nn = min(64, N - node0);
    const int j0 = cmat[(size_t)b * nblk];
    const int j1 = (b + 1 < nbuck) ? cmat[(size_t)(b + 1) * nblk] : E;

    if (threadIdx.x < 64) cnt[threadIdx.x] = 0;
    __syncthreads();
    for (int j = j0 + (int)threadIdx.x; j < j1; j += 256)
        atomicAdd(&cnt[ebuck[j].x & 63u], 1);
    __syncthreads();

    if (threadIdx.x < 64) {            // single wave: wave-synchronous scan
        const int myv = cnt[threadIdx.x];
        int v = myv;
#pragma unroll
        for (int d = 1; d < 64; d <<= 1) {
            const int t = __shfl_up(v, d, 64);
            if ((int)threadIdx.x >= d) v += t;
        }
        const int base = j0 + v - myv;   // exclusive
        cur[threadIdx.x] = base;
        if ((int)threadIdx.x < nn) offs[node0 + threadIdx.x] = base;
        if (threadIdx.x == 0 && b == nbuck - 1) offs[N] = E;
    }
    __syncthreads();

    for (int j = j0 + (int)threadIdx.x; j < j1; j += 256) {
        const uint2 ed = ebuck[j];
        const int pos = atomicAdd(&cur[ed.x & 63u], 1);
        ecsr[pos] = make_uint2(ed.x >> 6, ed.y);
    }
}

// ---------------- fused gather-aggregate (bf16 S) + bias + relu ----------------
// OUT_T = unsigned short (bf16, layers 1-2) or float (fp32, final layer).
// Round-7 loop structure: unrolled full-chunk body + tail, minimal liveness.
template <int D, int LOGT, bool RELU, typename OUT_T>
__global__ __launch_bounds__(256) void gather_agg_kernel(
    const unsigned short* __restrict__ S, const int* __restrict__ offs,
    const uint2* __restrict__ ecsr,
    const float* __restrict__ bias, OUT_T* __restrict__ out, int N)
{
    constexpr int TPN = 1 << LOGT;
    const int gid = blockIdx.x * 256 + threadIdx.x;
    const int node = gid >> LOGT;
    if (node >= N) return;
    const int lane = gid & (TPN - 1);
    const int c8 = lane << 3;

    const int j0 = offs[node];
    const int j1 = offs[node + 1];

    float acc[8];
#pragma unroll
    for (int c = 0; c < 8; ++c) acc[c] = 0.f;

    int jb = j0;
    // full chunks: compile-time trip count -> wide load issue
    for (; jb + TPN <= j1; jb += TPN) {
        const uint2 p = ecsr[jb + lane];
        const int myc = (int)p.x;
        const float myw = __uint_as_float(p.y);
#pragma unroll
        for (int t = 0; t < TPN; ++t) {
            const int s = __shfl(myc, t, TPN);
            const float w = __shfl(myw, t, TPN);
            const uint4 v = *(const uint4*)&S[(size_t)s * D + c8];
#pragma unroll
            for (int q = 0; q < 4; ++q) {
                const unsigned int u = (&v.x)[q];
                acc[q * 2 + 0] += w * __uint_as_float(u << 16);
                acc[q * 2 + 1] += w * __uint_as_float(u & 0xffff0000u);
            }
        }
    }
    if (jb < j1) {
        const int j = jb + lane;
        int myc = 0;
        float myw = 0.f;
        if (j < j1) {
            const uint2 p = ecsr[j];
            myc = (int)p.x;
            myw = __uint_as_float(p.y);
        }
        const int cnt = j1 - jb;
        for (int t = 0; t < cnt; ++t) {
            const int s = __shfl(myc, t, TPN);
            const float w = __shfl(myw, t, TPN);
            const uint4 v = *(const uint4*)&S[(size_t)s * D + c8];
#pragma unroll
            for (int q = 0; q < 4; ++q) {
                const unsigned int u = (&v.x)[q];
                acc[q * 2 + 0] += w * __uint_as_float(u << 16);
                acc[q * 2 + 1] += w * __uint_as_float(u & 0xffff0000u);
            }
        }
    }

#pragma unroll
    for (int c = 0; c < 8; ++c) {
        float v = acc[c] + bias[c8 + c];
        if (RELU) v = fmaxf(v, 0.f);
        acc[c] = v;
    }
    if constexpr (sizeof(OUT_T) == 2) {
        uint4 u;
        u.x = ((unsigned)f2bf(acc[1]) << 16) | (unsigned)f2bf(acc[0]);
        u.y = ((unsigned)f2bf(acc[3]) << 16) | (unsigned)f2bf(acc[2]);
        u.z = ((unsigned)f2bf(acc[5]) << 16) | (unsigned)f2bf(acc[4]);
        u.w = ((unsigned)f2bf(acc[7]) << 16) | (unsigned)f2bf(acc[6]);
        *(uint4*)&((unsigned short*)out)[(size_t)node * D + c8] = u;
    } else {
        float* op = (float*)out + (size_t)node * D + c8;
        *(float4*)op = make_float4(acc[0], acc[1], acc[2], acc[3]);
        *((float4*)op + 1) = make_float4(acc[4], acc[5], acc[6], acc[7]);
    }
}

extern "C" void kernel_launch(void* const* d_in, const int* in_sizes, int n_in,
                              void* d_out, int out_size, void* d_ws, size_t ws_size,
                              hipStream_t stream)
{
    const float* x    = (const float*)d_in[0];
    const int*   esrc = (const int*)  d_in[1];
    const int*   edst = (const int*)  d_in[2];
    const float* ew   = (const float*)d_in[3];
    const float* W1   = (const float*)d_in[4];
    const float* b1   = (const float*)d_in[5];
    const float* W2   = (const float*)d_in[6];
    const float* b2   = (const float*)d_in[7];
    const float* W3   = (const float*)d_in[8];
    const float* b3   = (const float*)d_in[9];

    const int N = in_sizes[0] / 256;   // 100000
    const int E = in_sizes[1];         // 1600000

    const int nbuck = (N + 63) >> 6;               // 1563
    const int nblk = (E + EPB - 1) / EPB;          // 196
    const int L = nbuck * nblk;

    // workspace layout (bf16 intermediates)
    unsigned short* Sb = (unsigned short*)d_ws;            // N*128 bf16 support
    unsigned short* Hb = Sb + (size_t)N * 128;             // N*128 bf16 hidden
    unsigned short* WT1 = Hb + (size_t)N * 128;
    unsigned short* WT2 = WT1 + 256 * 128;
    unsigned short* WT3 = WT2 + 128 * 64;
    uint2* ebuck = (uint2*)(WT3 + 64 * 64);                // E bucket-sorted
    uint2* ecsr  = ebuck + E;                              // E node-sorted (src, w)
    int* offs   = (int*)(ecsr + E);                        // N+1 (pad 4)
    int* cmat   = offs + N + 4;                            // nbuck*nblk
    int* psum   = cmat + ((L + 3) & ~3);                   // up to 1024
    float* out  = (float*)d_out;

    const dim3 blk(256);
    const int mblocks = (N + 127) / 128;                   // 782

    // ---- prep: weights + bucket sort + per-node offs ----
    wt_kernel<<<(45056 + 255) / 256, blk, 0, stream>>>(W1, W2, W3, WT1, WT2, WT3);
    count_kernel<<<nblk, blk, 0, stream>>>(edst, cmat, E, nblk, nbuck);
    scanA_kernel<<<(L + 1023) / 1024, blk, 0, stream>>>(cmat, psum, L);
    scanB_kernel<<<1, 1024, 0, stream>>>(psum, (L + 1023) / 1024);
    scanC_kernel<<<(L + 255) / 256, blk, 0, stream>>>(cmat, psum, L);
    place_kernel<<<nblk, blk, 0, stream>>>(esrc, edst, ew, cmat, ebuck, E, nblk, nbuck);
    sort2_kernel<<<nbuck, blk, 0, stream>>>(ebuck, cmat, offs, ecsr, N, nblk, nbuck, E);

    // ---- layer 1: 256 -> 128 ----
    mfma_gemm_kernel<128, false><<<mblocks, blk, 0, stream>>>(x, WT1, Sb, N, 256);
    gather_agg_kernel<128, 4, true, unsigned short><<<((N * 16) + 255) / 256, blk, 0, stream>>>(
        Sb, offs, ecsr, b1, Hb, N);

    // ---- layer 2: 128 -> 64 ----
    mfma_gemm_kernel<64, true><<<mblocks, blk, 0, stream>>>(Hb, WT2, Sb, N, 128);
    gather_agg_kernel<64, 3, true, unsigned short><<<((N * 8) + 255) / 256, blk, 0, stream>>>(
        Sb, offs, ecsr, b2, Hb, N);

    // ---- layer 3: 64 -> 64 ----
    mfma_gemm_kernel<64, true><<<mblocks, blk, 0, stream>>>(Hb, WT3, Sb, N, 64);
    gather_agg_kernel<64, 3, false, float><<<((N * 8) + 255) / 256, blk, 0, stream>>>(
        Sb, offs, ecsr, b3, out, N);
}